// Round 4
// baseline (69.288 us; speedup 1.0000x reference)
//
#include <hip/hip_runtime.h>

// Problem: B=4, P=12, H=W=32, K_STEP=12, NUM_CELLS=1024, TE_DEPTH=168, F=1192.
// Dtypes (established r0-r3): all float inputs fp32, TE int32, output fp32.
// R3 passed (absmax 3.9e-3, bf16-floor policy). rocprof r3: top-5 dispatches are
// all harness fillBuffer re-poisons (40us, 268MB each); our kernel <40us, so
// dur_us=69 is largely harness floor. This round: shrink the kernel's share.
//
// Structure change vs r3: 256 thr/block (4 waves, was 16), 4 cells/thread
// (rows h, h+8, h+16, h+24), so each of the 13 barriers syncs 4 waves not 16
// and per-thread ILP is 4x. `results` streamed to global inside the K-loop
// (no 13-deep register array); trans_prob/restart written in prologue; only
// the 132 LDS border cells are zeroed (interior overwritten by owners before
// first read -> one fewer barrier).
//
// Algorithm recap: one-hot matmuls collapse to row-gather + add
// (W[te_idx] + W[168+cell]); stencil cell (h,w) receives channel d of the
// neighbor at offset (dr,dc)_d; trans_prob loop-invariant -> 8 incoming-edge
// weights per cell in registers; padded 34x34 x-grid double-buffered in LDS.

namespace {
constexpr int PP  = 12;     // P
constexpr int NC  = 1024;   // 32*32
constexpr int TED = 168;    // TE_DEPTH
constexpr int KS  = 12;     // K_STEP
constexpr int PAD = 34;     // padded grid dim
// flat output offsets (elements), return order:
// Y(4096) | x(49152) | trans(393216) | restart(49152) | results(638976)
constexpr long O_X   = 4096;
constexpr long O_TP  = 53248;
constexpr long O_RP  = 446464;
constexpr long O_RES = 495616;
}

__global__ __launch_bounds__(256) void rwr_fused(
    const float* __restrict__ X,     // (B,P,32,32,1) fp32
    const int* __restrict__ TE,      // (B,24,2) int32
    const float* __restrict__ Wt,    // (1192,8) fp32
    const float* __restrict__ Wr,    // (1192,1) fp32
    const float* __restrict__ Wb,    // (1192,1) fp32
    float* __restrict__ out)         // fp32
{
    __shared__ float tp[NC * 8];         // trans_prob, 32 KB
    __shared__ float xb0[PAD * PAD];     // padded x grids, double-buffered
    __shared__ float xb1[PAD * PAD];

    const int bp = blockIdx.x;           // b*12 + p
    const int b  = bp / PP;
    const int p  = bp - b * PP;
    const int t  = threadIdx.x;          // 0..255
    const int w  = t & 31;
    const int r0 = t >> 5;               // 0..7; cells at rows r0+8i

    // zero ONLY the 132 border cells of both buffers; interior cells are
    // written by their owner threads below, before the single prologue barrier.
    if (t < 132) {
        int idx;
        if (t < 34)       idx = t;                       // top row
        else if (t < 68)  idx = 33 * PAD + (t - 34);     // bottom row
        else { const int j = t - 68;                     // left/right cols, rows 1..32
               idx = ((j >> 1) + 1) * PAD + ((j & 1) ? 33 : 0); }
        xb0[idx] = 0.f; xb1[idx] = 0.f;
    }

    const int te = TE[(b * 24 + p) * 2 + 0] * 24 + TE[(b * 24 + p) * 2 + 1];

    float x[4], xbias[4], rp[4];
    long  resbase[4];

    #pragma unroll
    for (int i = 0; i < 4; ++i) {
        const int  cell = t + 256 * i;
        const int  h    = r0 + 8 * i;
        const long gci  = (long)bp * NC + cell;

        // softmax over 8 logits; write trans_prob output + LDS immediately
        float pr[8]; float m = -1e30f;
        #pragma unroll
        for (int j = 0; j < 8; ++j) {
            pr[j] = Wt[te * 8 + j] + Wt[(TED + cell) * 8 + j];
            m = fmaxf(m, pr[j]);
        }
        float s = 0.f;
        #pragma unroll
        for (int j = 0; j < 8; ++j) { pr[j] = __expf(pr[j] - m); s += pr[j]; }
        const float inv = 1.f / s;
        #pragma unroll
        for (int j = 0; j < 8; ++j) {
            pr[j] *= inv;
            tp[cell * 8 + j] = pr[j];
            out[O_TP + gci * 8 + j] = pr[j];
        }

        rp[i] = 1.f / (1.f + __expf(-(Wr[te] + Wr[TED + cell])));
        out[O_RP + gci] = rp[i];

        const float x0 = X[bp * NC + cell];
        x[i]     = x0;
        xbias[i] = (Wb[te] + Wb[TED + cell]) * x0;
        xb0[(h + 1) * PAD + (w + 1)] = x0;

        resbase[i] = O_RES + gci * 13;
        out[resbase[i]] = x0;            // results[...,0] = x0
    }
    __syncthreads();   // tp + initial grid + zeroed borders visible

    // incoming-edge weights (loop-invariant): direction d, offset (dr,dc)_d.
    // OOB neighbors read x=0 from the border, weight value moot (index clamped).
    const int drr[8] = {-1,-1,-1, 0, 0, 1, 1, 1};
    const int dcc[8] = {-1, 0, 1,-1, 1,-1, 0, 1};
    float wn[4][8];
    #pragma unroll
    for (int i = 0; i < 4; ++i) {
        const int h = r0 + 8 * i;
        #pragma unroll
        for (int d = 0; d < 8; ++d) {
            const int nh = h + drr[d], nw = w + dcc[d];
            const bool ok = ((unsigned)nh < 32u) && ((unsigned)nw < 32u);
            const int nidx = ok ? (nh * 32 + nw) : 0;
            wn[i][d] = tp[nidx * 8 + d];
        }
    }

    float* cur = xb0;
    float* nxt = xb1;
    #pragma unroll
    for (int k = 0; k < KS; ++k) {
        #pragma unroll
        for (int i = 0; i < 4; ++i) {
            const int base = (r0 + 8 * i + 1) * PAD + (w + 1);
            float xt = 0.f;
            #pragma unroll
            for (int d = 0; d < 8; ++d)
                xt += wn[i][d] * cur[base + drr[d] * PAD + dcc[d]];
            x[i] = (1.f - rp[i]) * xt + rp[i] * x[i] + xbias[i];
            nxt[base] = x[i];
            out[resbase[i] + k + 1] = x[i];   // stream results[...,k+1]
        }
        float* tmp = cur; cur = nxt; nxt = tmp;
        __syncthreads();
    }

    // ---- epilogue: x_final and Y ----
    #pragma unroll
    for (int i = 0; i < 4; ++i) {
        const long gci = (long)bp * NC + t + 256 * i;
        out[O_X + gci] = x[i];
        if (p == PP - 1) out[(long)b * NC + t + 256 * i] = x[i];  // Y = x[:, -1]
    }
}

extern "C" void kernel_launch(void* const* d_in, const int* in_sizes, int n_in,
                              void* d_out, int out_size, void* d_ws, size_t ws_size,
                              hipStream_t stream) {
    const float* X  = (const float*)d_in[0];
    const int*   TE = (const int*)d_in[1];
    const float* Wt = (const float*)d_in[2];
    const float* Wr = (const float*)d_in[3];
    const float* Wb = (const float*)d_in[4];
    float* out = (float*)d_out;

    rwr_fused<<<dim3(4 * PP), dim3(256), 0, stream>>>(X, TE, Wt, Wr, Wb, out);
}